// Round 15
// baseline (255.090 us; speedup 1.0000x reference)
//
#include <hip/hip_runtime.h>
#include <math.h>

#define NB 4
#define NT 128
#define NS 512
#define NH 256

// pe/pq are prescaled by 2*log2(e) so exp(2z) == exp2(pe'+pq')
#define SCALE_2LOG2E 2.8853900817779268f

// MEASUREMENT ROUND: kernels identical to R14 but wrapped in repeat loops
// (kA x4, kB x8, kC x8) so each dispatch is >39us and appears in rocprof
// top-5 with full counters. True kernel time = dispatch_dur / rep.
// Deterministic: every rep recomputes and rewrites identical values.

__device__ __forceinline__ float fast_exp2(float x) {
#if __has_builtin(__builtin_amdgcn_exp2f)
    return __builtin_amdgcn_exp2f(x);
#else
    return __expf(x * 0.6931471805599453f);
#endif
}

__device__ __forceinline__ float fast_tanh(float x) {
    // tanh(x) = 1 - 2/(exp(2x)+1); safe at +/-inf
    float e = __expf(2.0f * x);
    return 1.0f - 2.0f / (e + 1.0f);
}

__device__ __forceinline__ float dot4(float4 a, float4 b, float acc) {
    acc = fmaf(a.x, b.x, acc);
    acc = fmaf(a.y, b.y, acc);
    acc = fmaf(a.z, b.z, acc);
    acc = fmaf(a.w, b.w, acc);
    return acc;
}

// ---------------------------------------------------------------------------
// 64x64-tile GEMM core (R10/R12, proven): both operands LDS, 4x4 reg tile.
// ---------------------------------------------------------------------------
__device__ __forceinline__ void gemm_tile_64x64(
    float4* __restrict__ wsh, float4* __restrict__ xsh,
    const float* __restrict__ Wp, int wstride,
    const float* __restrict__ Xp,
    int kchunks, int tid, float acc[4][4])
{
    const int o0 = (tid & 15) * 4;
    const int m0 = (tid >> 4) * 4;
    const int srow = tid >> 2, sjl = tid & 3;
    const int wslotx = (tid & 7);
    const int xslotx = ((tid >> 4) & 7);

    for (int ck = 0; ck < kchunks; ++ck) {
        __syncthreads();
        {
            const float4* src = reinterpret_cast<const float4*>(
                Wp + (size_t)srow * wstride + ck * 128);
            const int rsw = (srow >> 2) & 7;
#pragma unroll
            for (int k = 0; k < 8; ++k) {
                const int j = sjl + 4 * k;
                wsh[srow * 32 + ((j & 31) ^ rsw)] = src[j];
            }
        }
        {
            const float4* src = reinterpret_cast<const float4*>(
                Xp + (size_t)srow * NH + ck * 128);
            const int rsw = (srow >> 2) & 7;
#pragma unroll
            for (int k = 0; k < 8; ++k) {
                const int j = sjl + 4 * k;
                xsh[srow * 32 + ((j & 31) ^ rsw)] = src[j];
            }
        }
        __syncthreads();

#pragma unroll 4
        for (int k4 = 0; k4 < 32; ++k4) {
            float4 wv0 = wsh[(o0 + 0) * 32 + (k4 ^ wslotx)];
            float4 wv1 = wsh[(o0 + 1) * 32 + (k4 ^ wslotx)];
            float4 wv2 = wsh[(o0 + 2) * 32 + (k4 ^ wslotx)];
            float4 wv3 = wsh[(o0 + 3) * 32 + (k4 ^ wslotx)];
            float4 xv0 = xsh[(m0 + 0) * 32 + (k4 ^ xslotx)];
            float4 xv1 = xsh[(m0 + 1) * 32 + (k4 ^ xslotx)];
            float4 xv2 = xsh[(m0 + 2) * 32 + (k4 ^ xslotx)];
            float4 xv3 = xsh[(m0 + 3) * 32 + (k4 ^ xslotx)];
            acc[0][0] = dot4(xv0, wv0, acc[0][0]);
            acc[0][1] = dot4(xv0, wv1, acc[0][1]);
            acc[0][2] = dot4(xv0, wv2, acc[0][2]);
            acc[0][3] = dot4(xv0, wv3, acc[0][3]);
            acc[1][0] = dot4(xv1, wv0, acc[1][0]);
            acc[1][1] = dot4(xv1, wv1, acc[1][1]);
            acc[1][2] = dot4(xv1, wv2, acc[1][2]);
            acc[1][3] = dot4(xv1, wv3, acc[1][3]);
            acc[2][0] = dot4(xv2, wv0, acc[2][0]);
            acc[2][1] = dot4(xv2, wv1, acc[2][1]);
            acc[2][2] = dot4(xv2, wv2, acc[2][2]);
            acc[2][3] = dot4(xv2, wv3, acc[2][3]);
            acc[3][0] = dot4(xv3, wv0, acc[3][0]);
            acc[3][1] = dot4(xv3, wv1, acc[3][1]);
            acc[3][2] = dot4(xv3, wv2, acc[3][2]);
            acc[3][3] = dot4(xv3, wv3, acc[3][3]);
        }
    }
}

// ---------------------------------------------------------------------------
// kA: projections + W2 transpose (R14), repeated x4 for measurement.
// ---------------------------------------------------------------------------
__global__ __launch_bounds__(256, 2) void kA_proj(
    const float* __restrict__ enc, const float* __restrict__ q,
    const float* __restrict__ Wh, const float* __restrict__ Ws,
    const float* __restrict__ Wout, const float* __restrict__ v,
    float4* __restrict__ peP, float* __restrict__ pq,
    float* __restrict__ oq, float* __restrict__ w2t, float* __restrict__ w)
{
    __shared__ float4 wsh[64 * 32];
    __shared__ float4 xsh[64 * 32];

    const int bx = blockIdx.x;
    const int tid = threadIdx.x;

    for (int rep = 0; rep < 4; ++rep) {
        if (bx >= 192) {
            // transpose W2 tile (64 o x 64 k) via padded LDS
            float* tl = reinterpret_cast<float*>(wsh);   // 64*65*4 = 16.6 KB
            const int bi = bx - 192;
            const int oi = bi & 3, ki = bi >> 2;
            const int row = tid >> 2, jl = tid & 3;
            {
                const float4* src = reinterpret_cast<const float4*>(
                    Wout + (size_t)(oi * 64 + row) * (2 * NH) + NH + ki * 64);
#pragma unroll
                for (int kk = 0; kk < 4; ++kk) {
                    const int j = jl + 4 * kk;
                    const float4 val = src[j];
                    tl[(4 * j + 0) * 65 + row] = val.x;
                    tl[(4 * j + 1) * 65 + row] = val.y;
                    tl[(4 * j + 2) * 65 + row] = val.z;
                    tl[(4 * j + 3) * 65 + row] = val.w;
                }
            }
            __syncthreads();
            {
#pragma unroll
                for (int kk = 0; kk < 4; ++kk) {
                    const int j = jl + 4 * kk;
                    float4 val;
                    val.x = tl[row * 65 + 4 * j + 0];
                    val.y = tl[row * 65 + 4 * j + 1];
                    val.z = tl[row * 65 + 4 * j + 2];
                    val.w = tl[row * 65 + 4 * j + 3];
                    reinterpret_cast<float4*>(
                        w2t + (size_t)(ki * 64 + row) * NH + oi * 64)[j] = val;
                }
            }
        } else {
            float acc[4][4];
#pragma unroll
            for (int i = 0; i < 4; ++i)
#pragma unroll
                for (int j = 0; j < 4; ++j) acc[i][j] = 0.f;

            if (bx == 128) w[tid] = -2.0f * v[tid];

            const int o0 = (tid & 15) * 4;
            const int m0 = (tid >> 4) * 4;

            if (bx < 128) {
                const int mt = bx >> 2, ot = bx & 3;
                const int m_base = mt * 64;
                gemm_tile_64x64(wsh, xsh, Wh + (size_t)(ot * 64) * NH, NH,
                                enc + (size_t)m_base * NH, 2, tid, acc);
                const int b = m_base >> 9, s_base = m_base & (NS - 1);
                const int quad = ot * 16 + (tid & 15);
#pragma unroll
                for (int i = 0; i < 4; ++i) {
                    peP[(size_t)(b * 64 + quad) * NS + s_base + m0 + i] =
                        make_float4(acc[i][0] * SCALE_2LOG2E, acc[i][1] * SCALE_2LOG2E,
                                    acc[i][2] * SCALE_2LOG2E, acc[i][3] * SCALE_2LOG2E);
                }
            } else if (bx < 160) {
                const int bi = bx - 128;
                const int mt = bi >> 2, ot = bi & 3;
                const int m_base = mt * 64;
                gemm_tile_64x64(wsh, xsh, Ws + (size_t)(ot * 64) * NH, NH,
                                q + (size_t)m_base * NH, 2, tid, acc);
#pragma unroll
                for (int i = 0; i < 4; ++i) {
                    *reinterpret_cast<float4*>(
                        pq + (size_t)(m_base + m0 + i) * NH + ot * 64 + o0) =
                        make_float4(acc[i][0] * SCALE_2LOG2E, acc[i][1] * SCALE_2LOG2E,
                                    acc[i][2] * SCALE_2LOG2E, acc[i][3] * SCALE_2LOG2E);
                }
            } else {
                const int bi = bx - 160;
                const int mt = bi >> 2, ot = bi & 3;
                const int m_base = mt * 64;
                gemm_tile_64x64(wsh, xsh, Wout + (size_t)(ot * 64) * (2 * NH), 2 * NH,
                                q + (size_t)m_base * NH, 2, tid, acc);
#pragma unroll
                for (int i = 0; i < 4; ++i) {
                    *reinterpret_cast<float4*>(
                        oq + (size_t)(m_base + m0 + i) * NH + ot * 64 + o0) =
                        make_float4(acc[i][0], acc[i][1], acc[i][2], acc[i][3]);
                }
            }
        }
        __syncthreads();   // cross-rep LDS hazard guard
    }
}

// ---------------------------------------------------------------------------
// kB: scores (R12), repeated x8 for measurement.
// ---------------------------------------------------------------------------
__global__ __launch_bounds__(512) void kB_score(
    const float4* __restrict__ peP, const float* __restrict__ pq,
    const float* __restrict__ w, float* __restrict__ e)
{
    __shared__ float4 pp[64 * 64];    // 64 KB
    __shared__ float4 pqs[16 * 64];   // 16 KB
    __shared__ float4 wls[64];        // 1 KB

    const int sx = blockIdx.x;
    const int ty = blockIdx.y;
    const int b  = blockIdx.z;
    const int tid = threadIdx.x;
    const int t0 = ty * 16;

    for (int rep = 0; rep < 8; ++rep) {
        {
            const int row = tid >> 3, jl = tid & 7;
            const float4* src = peP + (size_t)(b * 64 + row) * NS + sx * 64;
#pragma unroll
            for (int k = 0; k < 8; ++k) pp[row * 64 + jl + 8 * k] = src[jl + 8 * k];
        }
        {
            const int r = tid >> 5, j = tid & 31;
            const float4* src = reinterpret_cast<const float4*>(
                pq + (size_t)(b * NT + t0 + r) * NH);
            pqs[r * 64 + j] = src[j];
            pqs[r * 64 + j + 32] = src[j + 32];
        }
        if (tid < 64) wls[tid] = reinterpret_cast<const float4*>(w)[tid];
        __syncthreads();

        const int lane = tid & 63;
        const int wvi  = tid >> 6;
        const int tA = wvi, tB = wvi + 8;

        float a0 = 0.f, a1 = 0.f, a2 = 0.f, a3 = 0.f;
        float b0 = 0.f, b1 = 0.f, b2 = 0.f, b3 = 0.f;
#pragma unroll 4
        for (int h4 = 0; h4 < 64; ++h4) {
            const float4 pv = pp[h4 * 64 + lane];
            const float4 qa = pqs[tA * 64 + h4];
            const float4 qb = pqs[tB * 64 + h4];
            const float4 wl = wls[h4];
            a0 = fmaf(wl.x, __builtin_amdgcn_rcpf(fast_exp2(pv.x + qa.x) + 1.0f), a0);
            a1 = fmaf(wl.y, __builtin_amdgcn_rcpf(fast_exp2(pv.y + qa.y) + 1.0f), a1);
            a2 = fmaf(wl.z, __builtin_amdgcn_rcpf(fast_exp2(pv.z + qa.z) + 1.0f), a2);
            a3 = fmaf(wl.w, __builtin_amdgcn_rcpf(fast_exp2(pv.w + qa.w) + 1.0f), a3);
            b0 = fmaf(wl.x, __builtin_amdgcn_rcpf(fast_exp2(pv.x + qb.x) + 1.0f), b0);
            b1 = fmaf(wl.y, __builtin_amdgcn_rcpf(fast_exp2(pv.y + qb.y) + 1.0f), b1);
            b2 = fmaf(wl.z, __builtin_amdgcn_rcpf(fast_exp2(pv.z + qb.z) + 1.0f), b2);
            b3 = fmaf(wl.w, __builtin_amdgcn_rcpf(fast_exp2(pv.w + qb.w) + 1.0f), b3);
        }
        e[(size_t)(b * NT + t0 + tA) * NS + sx * 64 + lane] = (a0 + a1) + (a2 + a3);
        e[(size_t)(b * NT + t0 + tB) * NS + sx * 64 + lane] = (b0 + b1) + (b2 + b3);
        __syncthreads();   // cross-rep LDS hazard guard
    }
}

// ---------------------------------------------------------------------------
// kC: fused softmax + context + output (R12), repeated x8 for measurement.
// ---------------------------------------------------------------------------
__global__ __launch_bounds__(512) void kC_ctx_out(
    const float* __restrict__ e, const float* __restrict__ enc,
    const int* __restrict__ lens, const float* __restrict__ w2t,
    const float* __restrict__ oq, float* __restrict__ out)
{
    __shared__ __align__(16) unsigned char smem[45088];
    float4* pt    = reinterpret_cast<float4*>(smem);            // 8 KB [512]
    float*  cpart = reinterpret_cast<float*>(smem + 8192);      // 32 KB
    float4* opart = reinterpret_cast<float4*>(smem + 8192);     // alias
    float4* ct4   = reinterpret_cast<float4*>(smem + 40960);    // 4 KB
    float*  rs    = reinterpret_cast<float*>(smem + 45056);     // 16 B

    const int tt = blockIdx.x;
    const int b  = blockIdx.y;
    const int tid = threadIdx.x;
    const int lane = tid & 63;
    const int wvi  = tid >> 6;
    const int tbase = tt * 4;
    const int len = lens[b];

    for (int rep = 0; rep < 8; ++rep) {
        if (wvi < 4) {
            const int t = tbase + wvi;
            const float4* erow = reinterpret_cast<const float4*>(
                e + (size_t)(b * NT + t) * NS);
            float4 va = erow[lane];
            float4 vb = erow[lane + 64];
            const int c0 = 4 * lane, c1 = 256 + 4 * lane;
            if (c0 + 0 >= len) va.x = -INFINITY;
            if (c0 + 1 >= len) va.y = -INFINITY;
            if (c0 + 2 >= len) va.z = -INFINITY;
            if (c0 + 3 >= len) va.w = -INFINITY;
            if (c1 + 0 >= len) vb.x = -INFINITY;
            if (c1 + 1 >= len) vb.y = -INFINITY;
            if (c1 + 2 >= len) vb.z = -INFINITY;
            if (c1 + 3 >= len) vb.w = -INFINITY;

            float m = fmaxf(fmaxf(fmaxf(va.x, va.y), fmaxf(va.z, va.w)),
                            fmaxf(fmaxf(vb.x, vb.y), fmaxf(vb.z, vb.w)));
#pragma unroll
            for (int off = 32; off; off >>= 1) m = fmaxf(m, __shfl_xor(m, off));

            va.x = __expf(va.x - m); va.y = __expf(va.y - m);
            va.z = __expf(va.z - m); va.w = __expf(va.w - m);
            vb.x = __expf(vb.x - m); vb.y = __expf(vb.y - m);
            vb.z = __expf(vb.z - m); vb.w = __expf(vb.w - m);

            float sum = va.x + va.y + va.z + va.w + vb.x + vb.y + vb.z + vb.w;
#pragma unroll
            for (int off = 32; off; off >>= 1) sum += __shfl_xor(sum, off);
            if (lane == 0) rs[wvi] = 1.0f / sum;

            float* ptf = reinterpret_cast<float*>(pt);
            ptf[(c0 + 0) * 4 + wvi] = va.x;
            ptf[(c0 + 1) * 4 + wvi] = va.y;
            ptf[(c0 + 2) * 4 + wvi] = va.z;
            ptf[(c0 + 3) * 4 + wvi] = va.w;
            ptf[(c1 + 0) * 4 + wvi] = vb.x;
            ptf[(c1 + 1) * 4 + wvi] = vb.y;
            ptf[(c1 + 2) * 4 + wvi] = vb.z;
            ptf[(c1 + 3) * 4 + wvi] = vb.w;
        }
        __syncthreads();

        {
            const float4* enc4 = reinterpret_cast<const float4*>(
                enc + (size_t)b * NS * NH) + (size_t)wvi * 64 * 64 + lane;
            float4 ac0 = make_float4(0, 0, 0, 0), ac1 = ac0, ac2 = ac0, ac3 = ac0;
#pragma unroll 4
            for (int si = 0; si < 64; ++si) {
                const float4 xe = enc4[(size_t)si * 64];
                const float4 al = pt[wvi * 64 + si];
                ac0.x = fmaf(al.x, xe.x, ac0.x); ac0.y = fmaf(al.x, xe.y, ac0.y);
                ac0.z = fmaf(al.x, xe.z, ac0.z); ac0.w = fmaf(al.x, xe.w, ac0.w);
                ac1.x = fmaf(al.y, xe.x, ac1.x); ac1.y = fmaf(al.y, xe.y, ac1.y);
                ac1.z = fmaf(al.y, xe.z, ac1.z); ac1.w = fmaf(al.y, xe.w, ac1.w);
                ac2.x = fmaf(al.z, xe.x, ac2.x); ac2.y = fmaf(al.z, xe.y, ac2.y);
                ac2.z = fmaf(al.z, xe.z, ac2.z); ac2.w = fmaf(al.z, xe.w, ac2.w);
                ac3.x = fmaf(al.w, xe.x, ac3.x); ac3.y = fmaf(al.w, xe.y, ac3.y);
                ac3.z = fmaf(al.w, xe.z, ac3.z); ac3.w = fmaf(al.w, xe.w, ac3.w);
            }
            float4* cp = reinterpret_cast<float4*>(cpart);
            cp[(wvi * 4 + 0) * 64 + lane] = ac0;
            cp[(wvi * 4 + 1) * 64 + lane] = ac1;
            cp[(wvi * 4 + 2) * 64 + lane] = ac2;
            cp[(wvi * 4 + 3) * 64 + lane] = ac3;
        }
        __syncthreads();

        if (tid < 256) {
            const int h = tid;
            float v0 = 0.f, v1 = 0.f, v2 = 0.f, v3 = 0.f;
#pragma unroll
            for (int sg = 0; sg < 8; ++sg) {
                v0 += cpart[(sg * 4 + 0) * 256 + h];
                v1 += cpart[(sg * 4 + 1) * 256 + h];
                v2 += cpart[(sg * 4 + 2) * 256 + h];
                v3 += cpart[(sg * 4 + 3) * 256 + h];
            }
            ct4[h] = make_float4(v0 * rs[0], v1 * rs[1], v2 * rs[2], v3 * rs[3]);
        }
        __syncthreads();

        {
            const float4* w2t4 = reinterpret_cast<const float4*>(w2t);
            float4 op0 = make_float4(0, 0, 0, 0), op1 = op0, op2 = op0, op3 = op0;
#pragma unroll 4
            for (int hi = 0; hi < 32; ++hi) {
                const int h = wvi * 32 + hi;
                const float4 wv4 = w2t4[(size_t)h * 64 + lane];
                const float4 cl = ct4[h];
                op0.x = fmaf(cl.x, wv4.x, op0.x); op0.y = fmaf(cl.x, wv4.y, op0.y);
                op0.z = fmaf(cl.x, wv4.z, op0.z); op0.w = fmaf(cl.x, wv4.w, op0.w);
                op1.x = fmaf(cl.y, wv4.x, op1.x); op1.y = fmaf(cl.y, wv4.y, op1.y);
                op1.z = fmaf(cl.y, wv4.z, op1.z); op1.w = fmaf(cl.y, wv4.w, op1.w);
                op2.x = fmaf(cl.z, wv4.x, op2.x); op2.y = fmaf(cl.z, wv4.y, op2.y);
                op2.z = fmaf(cl.z, wv4.z, op2.z); op2.w = fmaf(cl.z, wv4.w, op2.w);
                op3.x = fmaf(cl.w, wv4.x, op3.x); op3.y = fmaf(cl.w, wv4.y, op3.y);
                op3.z = fmaf(cl.w, wv4.z, op3.z); op3.w = fmaf(cl.w, wv4.w, op3.w);
            }
            opart[(wvi * 4 + 0) * 64 + lane] = op0;
            opart[(wvi * 4 + 1) * 64 + lane] = op1;
            opart[(wvi * 4 + 2) * 64 + lane] = op2;
            opart[(wvi * 4 + 3) * 64 + lane] = op3;
        }
        __syncthreads();

        if (tid < 256) {
            const int o4 = tid & 63, tl2 = tid >> 6;
            float4 s = make_float4(0, 0, 0, 0);
#pragma unroll
            for (int kg = 0; kg < 8; ++kg) {
                const float4 p = opart[(kg * 4 + tl2) * 64 + o4];
                s.x += p.x; s.y += p.y; s.z += p.z; s.w += p.w;
            }
            const int t = tbase + tl2;
            const float4 qo = reinterpret_cast<const float4*>(
                oq + (size_t)(b * NT + t) * NH)[o4];
            float4 r;
            r.x = fast_tanh(s.x + qo.x);
            r.y = fast_tanh(s.y + qo.y);
            r.z = fast_tanh(s.z + qo.z);
            r.w = fast_tanh(s.w + qo.w);
            reinterpret_cast<float4*>(out + (size_t)(b * NT + t) * NH)[o4] = r;
        }
        __syncthreads();   // cross-rep LDS hazard guard
    }
}

extern "C" void kernel_launch(void* const* d_in, const int* in_sizes, int n_in,
                              void* d_out, int out_size, void* d_ws, size_t ws_size,
                              hipStream_t stream) {
    const float* q    = (const float*)d_in[0];  // (B,T,H)
    const float* enc  = (const float*)d_in[1];  // (B,S,H)
    const int*   lens = (const int*)d_in[2];    // (B,)
    const float* Ws   = (const float*)d_in[3];  // (H,H)
    const float* Wh   = (const float*)d_in[4];  // (H,H)
    const float* v    = (const float*)d_in[5];  // (H,)
    const float* Wout = (const float*)d_in[6];  // (H,2H)
    float* out = (float*)d_out;                 // (B,T,H)

    float4* peP = (float4*)d_ws;                       // NB*64*NS f4
    float* pq  = (float*)d_ws + (size_t)NB * NH * NS;  // NB*NT*NH
    float* oq  = pq + (size_t)NB * NT * NH;            // NB*NT*NH
    float* w2t = oq + (size_t)NB * NT * NH;            // NH*NH
    float* w   = w2t + (size_t)NH * NH;                // NH
    float* e   = w + NH;                               // NB*NT*NS

    kA_proj<<<208, 256, 0, stream>>>(enc, q, Wh, Ws, Wout, v, peP, pq, oq, w2t, w);
    kB_score<<<dim3(8, 8, 4), 512, 0, stream>>>(peP, pq, w, e);
    kC_ctx_out<<<dim3(32, 4), 512, 0, stream>>>(e, enc, lens, w2t, oq, out);
}

// Round 16
// 46.009 us; speedup vs baseline: 5.5444x; 5.5444x over previous
//
#include <hip/hip_runtime.h>
#include <math.h>

#define NB 4
#define NT 128
#define NS 512
#define NH 256

// pe/pq are prescaled by 2*log2(e) so exp(2z) == exp2(pe'+pq')
#define SCALE_2LOG2E 2.8853900817779268f

__device__ __forceinline__ float fast_exp2(float x) {
#if __has_builtin(__builtin_amdgcn_exp2f)
    return __builtin_amdgcn_exp2f(x);
#else
    return __expf(x * 0.6931471805599453f);
#endif
}

__device__ __forceinline__ float fast_tanh(float x) {
    // tanh(x) = 1 - 2/(exp(2x)+1); safe at +/-inf
    float e = __expf(2.0f * x);
    return 1.0f - 2.0f / (e + 1.0f);
}

__device__ __forceinline__ float dot4(float4 a, float4 b, float acc) {
    acc = fmaf(a.x, b.x, acc);
    acc = fmaf(a.y, b.y, acc);
    acc = fmaf(a.z, b.z, acc);
    acc = fmaf(a.w, b.w, acc);
    return acc;
}

// ---------------------------------------------------------------------------
// 64x64-tile GEMM core (R10/R12, proven): both operands LDS, 4x4 reg tile.
// ---------------------------------------------------------------------------
__device__ __forceinline__ void gemm_tile_64x64(
    float4* __restrict__ wsh, float4* __restrict__ xsh,
    const float* __restrict__ Wp, int wstride,
    const float* __restrict__ Xp,
    int kchunks, int tid, float acc[4][4])
{
    const int o0 = (tid & 15) * 4;
    const int m0 = (tid >> 4) * 4;
    const int srow = tid >> 2, sjl = tid & 3;
    const int wslotx = (tid & 7);
    const int xslotx = ((tid >> 4) & 7);

    for (int ck = 0; ck < kchunks; ++ck) {
        __syncthreads();
        {
            const float4* src = reinterpret_cast<const float4*>(
                Wp + (size_t)srow * wstride + ck * 128);
            const int rsw = (srow >> 2) & 7;
#pragma unroll
            for (int k = 0; k < 8; ++k) {
                const int j = sjl + 4 * k;
                wsh[srow * 32 + ((j & 31) ^ rsw)] = src[j];
            }
        }
        {
            const float4* src = reinterpret_cast<const float4*>(
                Xp + (size_t)srow * NH + ck * 128);
            const int rsw = (srow >> 2) & 7;
#pragma unroll
            for (int k = 0; k < 8; ++k) {
                const int j = sjl + 4 * k;
                xsh[srow * 32 + ((j & 31) ^ rsw)] = src[j];
            }
        }
        __syncthreads();

#pragma unroll 4
        for (int k4 = 0; k4 < 32; ++k4) {
            float4 wv0 = wsh[(o0 + 0) * 32 + (k4 ^ wslotx)];
            float4 wv1 = wsh[(o0 + 1) * 32 + (k4 ^ wslotx)];
            float4 wv2 = wsh[(o0 + 2) * 32 + (k4 ^ wslotx)];
            float4 wv3 = wsh[(o0 + 3) * 32 + (k4 ^ wslotx)];
            float4 xv0 = xsh[(m0 + 0) * 32 + (k4 ^ xslotx)];
            float4 xv1 = xsh[(m0 + 1) * 32 + (k4 ^ xslotx)];
            float4 xv2 = xsh[(m0 + 2) * 32 + (k4 ^ xslotx)];
            float4 xv3 = xsh[(m0 + 3) * 32 + (k4 ^ xslotx)];
            acc[0][0] = dot4(xv0, wv0, acc[0][0]);
            acc[0][1] = dot4(xv0, wv1, acc[0][1]);
            acc[0][2] = dot4(xv0, wv2, acc[0][2]);
            acc[0][3] = dot4(xv0, wv3, acc[0][3]);
            acc[1][0] = dot4(xv1, wv0, acc[1][0]);
            acc[1][1] = dot4(xv1, wv1, acc[1][1]);
            acc[1][2] = dot4(xv1, wv2, acc[1][2]);
            acc[1][3] = dot4(xv1, wv3, acc[1][3]);
            acc[2][0] = dot4(xv2, wv0, acc[2][0]);
            acc[2][1] = dot4(xv2, wv1, acc[2][1]);
            acc[2][2] = dot4(xv2, wv2, acc[2][2]);
            acc[2][3] = dot4(xv2, wv3, acc[2][3]);
            acc[3][0] = dot4(xv3, wv0, acc[3][0]);
            acc[3][1] = dot4(xv3, wv1, acc[3][1]);
            acc[3][2] = dot4(xv3, wv2, acc[3][2]);
            acc[3][3] = dot4(xv3, wv3, acc[3][3]);
        }
    }
}

// ---------------------------------------------------------------------------
// kA: projections + W2 transpose (R14, proven).
// ---------------------------------------------------------------------------
__global__ __launch_bounds__(256, 2) void kA_proj(
    const float* __restrict__ enc, const float* __restrict__ q,
    const float* __restrict__ Wh, const float* __restrict__ Ws,
    const float* __restrict__ Wout, const float* __restrict__ v,
    float4* __restrict__ peP, float* __restrict__ pq,
    float* __restrict__ oq, float* __restrict__ w2t, float* __restrict__ w)
{
    __shared__ float4 wsh[64 * 32];
    __shared__ float4 xsh[64 * 32];

    const int bx = blockIdx.x;
    const int tid = threadIdx.x;

    if (bx >= 192) {
        // transpose W2 tile (64 o x 64 k) via padded LDS
        float* tl = reinterpret_cast<float*>(wsh);   // 64*65*4 = 16.6 KB
        const int bi = bx - 192;
        const int oi = bi & 3, ki = bi >> 2;
        const int row = tid >> 2, jl = tid & 3;
        {
            const float4* src = reinterpret_cast<const float4*>(
                Wout + (size_t)(oi * 64 + row) * (2 * NH) + NH + ki * 64);
#pragma unroll
            for (int kk = 0; kk < 4; ++kk) {
                const int j = jl + 4 * kk;
                const float4 val = src[j];
                tl[(4 * j + 0) * 65 + row] = val.x;
                tl[(4 * j + 1) * 65 + row] = val.y;
                tl[(4 * j + 2) * 65 + row] = val.z;
                tl[(4 * j + 3) * 65 + row] = val.w;
            }
        }
        __syncthreads();
        {
#pragma unroll
            for (int kk = 0; kk < 4; ++kk) {
                const int j = jl + 4 * kk;
                float4 val;
                val.x = tl[row * 65 + 4 * j + 0];
                val.y = tl[row * 65 + 4 * j + 1];
                val.z = tl[row * 65 + 4 * j + 2];
                val.w = tl[row * 65 + 4 * j + 3];
                reinterpret_cast<float4*>(
                    w2t + (size_t)(ki * 64 + row) * NH + oi * 64)[j] = val;
            }
        }
        return;
    }

    float acc[4][4];
#pragma unroll
    for (int i = 0; i < 4; ++i)
#pragma unroll
        for (int j = 0; j < 4; ++j) acc[i][j] = 0.f;

    if (bx == 128) w[tid] = -2.0f * v[tid];

    const int o0 = (tid & 15) * 4;
    const int m0 = (tid >> 4) * 4;

    if (bx < 128) {
        const int mt = bx >> 2, ot = bx & 3;
        const int m_base = mt * 64;
        gemm_tile_64x64(wsh, xsh, Wh + (size_t)(ot * 64) * NH, NH,
                        enc + (size_t)m_base * NH, 2, tid, acc);
        const int b = m_base >> 9, s_base = m_base & (NS - 1);
        const int quad = ot * 16 + (tid & 15);
#pragma unroll
        for (int i = 0; i < 4; ++i) {
            peP[(size_t)(b * 64 + quad) * NS + s_base + m0 + i] =
                make_float4(acc[i][0] * SCALE_2LOG2E, acc[i][1] * SCALE_2LOG2E,
                            acc[i][2] * SCALE_2LOG2E, acc[i][3] * SCALE_2LOG2E);
        }
    } else if (bx < 160) {
        const int bi = bx - 128;
        const int mt = bi >> 2, ot = bi & 3;
        const int m_base = mt * 64;
        gemm_tile_64x64(wsh, xsh, Ws + (size_t)(ot * 64) * NH, NH,
                        q + (size_t)m_base * NH, 2, tid, acc);
#pragma unroll
        for (int i = 0; i < 4; ++i) {
            *reinterpret_cast<float4*>(
                pq + (size_t)(m_base + m0 + i) * NH + ot * 64 + o0) =
                make_float4(acc[i][0] * SCALE_2LOG2E, acc[i][1] * SCALE_2LOG2E,
                            acc[i][2] * SCALE_2LOG2E, acc[i][3] * SCALE_2LOG2E);
        }
    } else {
        const int bi = bx - 160;
        const int mt = bi >> 2, ot = bi & 3;
        const int m_base = mt * 64;
        gemm_tile_64x64(wsh, xsh, Wout + (size_t)(ot * 64) * (2 * NH), 2 * NH,
                        q + (size_t)m_base * NH, 2, tid, acc);
#pragma unroll
        for (int i = 0; i < 4; ++i) {
            *reinterpret_cast<float4*>(
                oq + (size_t)(m_base + m0 + i) * NH + ot * 64 + o0) =
                make_float4(acc[i][0], acc[i][1], acc[i][2], acc[i][3]);
        }
    }
}

// ---------------------------------------------------------------------------
// kB v2: scores, 2 t-rows per thread; pp staged in TWO 32 KB chunks so
// LDS = 32+16+1 = 49 KB -> 2 blocks/CU (R15 showed 81 KB capped us at
// 1 block/CU, 22% occupancy, 16.2 us). Accumulators carry across chunks.
// ---------------------------------------------------------------------------
__global__ __launch_bounds__(512) void kB_score(
    const float4* __restrict__ peP, const float* __restrict__ pq,
    const float* __restrict__ w, float* __restrict__ e)
{
    __shared__ float4 pp[32 * 64];    // 32 KB (one h4-chunk)
    __shared__ float4 pqs[16 * 64];   // 16 KB
    __shared__ float4 wls[64];        // 1 KB

    const int sx = blockIdx.x;
    const int ty = blockIdx.y;
    const int b  = blockIdx.z;
    const int tid = threadIdx.x;
    const int t0 = ty * 16;

    {
        const int r = tid >> 5, j = tid & 31;
        const float4* src = reinterpret_cast<const float4*>(
            pq + (size_t)(b * NT + t0 + r) * NH);
        pqs[r * 64 + j] = src[j];
        pqs[r * 64 + j + 32] = src[j + 32];
    }
    if (tid < 64) wls[tid] = reinterpret_cast<const float4*>(w)[tid];

    const int lane = tid & 63;
    const int wvi  = tid >> 6;
    const int tA = wvi, tB = wvi + 8;

    float a0 = 0.f, a1 = 0.f, a2 = 0.f, a3 = 0.f;
    float b0 = 0.f, b1 = 0.f, b2 = 0.f, b3 = 0.f;

#pragma unroll
    for (int ch = 0; ch < 2; ++ch) {
        __syncthreads();   // prior chunk fully consumed (and pqs/wls staged)
        {
            // stage 32 h4-rows x 64 s-f4: 16 thr/row x 4 f4 each, coalesced
            const int row = tid >> 4, jl = tid & 15;
            const float4* src = peP + (size_t)(b * 64 + ch * 32 + row) * NS + sx * 64;
#pragma unroll
            for (int k = 0; k < 4; ++k) pp[row * 64 + jl + 16 * k] = src[jl + 16 * k];
        }
        __syncthreads();

#pragma unroll 4
        for (int h4l = 0; h4l < 32; ++h4l) {
            const int h4 = ch * 32 + h4l;
            const float4 pv = pp[h4l * 64 + lane];
            const float4 qa = pqs[tA * 64 + h4];
            const float4 qb = pqs[tB * 64 + h4];
            const float4 wl = wls[h4];
            a0 = fmaf(wl.x, __builtin_amdgcn_rcpf(fast_exp2(pv.x + qa.x) + 1.0f), a0);
            a1 = fmaf(wl.y, __builtin_amdgcn_rcpf(fast_exp2(pv.y + qa.y) + 1.0f), a1);
            a2 = fmaf(wl.z, __builtin_amdgcn_rcpf(fast_exp2(pv.z + qa.z) + 1.0f), a2);
            a3 = fmaf(wl.w, __builtin_amdgcn_rcpf(fast_exp2(pv.w + qa.w) + 1.0f), a3);
            b0 = fmaf(wl.x, __builtin_amdgcn_rcpf(fast_exp2(pv.x + qb.x) + 1.0f), b0);
            b1 = fmaf(wl.y, __builtin_amdgcn_rcpf(fast_exp2(pv.y + qb.y) + 1.0f), b1);
            b2 = fmaf(wl.z, __builtin_amdgcn_rcpf(fast_exp2(pv.z + qb.z) + 1.0f), b2);
            b3 = fmaf(wl.w, __builtin_amdgcn_rcpf(fast_exp2(pv.w + qb.w) + 1.0f), b3);
        }
    }
    e[(size_t)(b * NT + t0 + tA) * NS + sx * 64 + lane] = (a0 + a1) + (a2 + a3);
    e[(size_t)(b * NT + t0 + tB) * NS + sx * 64 + lane] = (b0 + b1) + (b2 + b3);
}

// ---------------------------------------------------------------------------
// kC: fused masked-softmax + context + output projection (R12, proven).
// ---------------------------------------------------------------------------
__global__ __launch_bounds__(512) void kC_ctx_out(
    const float* __restrict__ e, const float* __restrict__ enc,
    const int* __restrict__ lens, const float* __restrict__ w2t,
    const float* __restrict__ oq, float* __restrict__ out)
{
    __shared__ __align__(16) unsigned char smem[45088];
    float4* pt    = reinterpret_cast<float4*>(smem);            // 8 KB [512]
    float*  cpart = reinterpret_cast<float*>(smem + 8192);      // 32 KB
    float4* opart = reinterpret_cast<float4*>(smem + 8192);     // alias
    float4* ct4   = reinterpret_cast<float4*>(smem + 40960);    // 4 KB
    float*  rs    = reinterpret_cast<float*>(smem + 45056);     // 16 B

    const int tt = blockIdx.x;
    const int b  = blockIdx.y;
    const int tid = threadIdx.x;
    const int lane = tid & 63;
    const int wvi  = tid >> 6;
    const int tbase = tt * 4;
    const int len = lens[b];

    if (wvi < 4) {
        const int t = tbase + wvi;
        const float4* erow = reinterpret_cast<const float4*>(
            e + (size_t)(b * NT + t) * NS);
        float4 va = erow[lane];
        float4 vb = erow[lane + 64];
        const int c0 = 4 * lane, c1 = 256 + 4 * lane;
        if (c0 + 0 >= len) va.x = -INFINITY;
        if (c0 + 1 >= len) va.y = -INFINITY;
        if (c0 + 2 >= len) va.z = -INFINITY;
        if (c0 + 3 >= len) va.w = -INFINITY;
        if (c1 + 0 >= len) vb.x = -INFINITY;
        if (c1 + 1 >= len) vb.y = -INFINITY;
        if (c1 + 2 >= len) vb.z = -INFINITY;
        if (c1 + 3 >= len) vb.w = -INFINITY;

        float m = fmaxf(fmaxf(fmaxf(va.x, va.y), fmaxf(va.z, va.w)),
                        fmaxf(fmaxf(vb.x, vb.y), fmaxf(vb.z, vb.w)));
#pragma unroll
        for (int off = 32; off; off >>= 1) m = fmaxf(m, __shfl_xor(m, off));

        va.x = __expf(va.x - m); va.y = __expf(va.y - m);
        va.z = __expf(va.z - m); va.w = __expf(va.w - m);
        vb.x = __expf(vb.x - m); vb.y = __expf(vb.y - m);
        vb.z = __expf(vb.z - m); vb.w = __expf(vb.w - m);

        float sum = va.x + va.y + va.z + va.w + vb.x + vb.y + vb.z + vb.w;
#pragma unroll
        for (int off = 32; off; off >>= 1) sum += __shfl_xor(sum, off);
        if (lane == 0) rs[wvi] = 1.0f / sum;

        float* ptf = reinterpret_cast<float*>(pt);
        ptf[(c0 + 0) * 4 + wvi] = va.x;
        ptf[(c0 + 1) * 4 + wvi] = va.y;
        ptf[(c0 + 2) * 4 + wvi] = va.z;
        ptf[(c0 + 3) * 4 + wvi] = va.w;
        ptf[(c1 + 0) * 4 + wvi] = vb.x;
        ptf[(c1 + 1) * 4 + wvi] = vb.y;
        ptf[(c1 + 2) * 4 + wvi] = vb.z;
        ptf[(c1 + 3) * 4 + wvi] = vb.w;
    }
    __syncthreads();

    {
        const float4* enc4 = reinterpret_cast<const float4*>(
            enc + (size_t)b * NS * NH) + (size_t)wvi * 64 * 64 + lane;
        float4 ac0 = make_float4(0, 0, 0, 0), ac1 = ac0, ac2 = ac0, ac3 = ac0;
#pragma unroll 4
        for (int si = 0; si < 64; ++si) {
            const float4 xe = enc4[(size_t)si * 64];
            const float4 al = pt[wvi * 64 + si];
            ac0.x = fmaf(al.x, xe.x, ac0.x); ac0.y = fmaf(al.x, xe.y, ac0.y);
            ac0.z = fmaf(al.x, xe.z, ac0.z); ac0.w = fmaf(al.x, xe.w, ac0.w);
            ac1.x = fmaf(al.y, xe.x, ac1.x); ac1.y = fmaf(al.y, xe.y, ac1.y);
            ac1.z = fmaf(al.y, xe.z, ac1.z); ac1.w = fmaf(al.y, xe.w, ac1.w);
            ac2.x = fmaf(al.z, xe.x, ac2.x); ac2.y = fmaf(al.z, xe.y, ac2.y);
            ac2.z = fmaf(al.z, xe.z, ac2.z); ac2.w = fmaf(al.z, xe.w, ac2.w);
            ac3.x = fmaf(al.w, xe.x, ac3.x); ac3.y = fmaf(al.w, xe.y, ac3.y);
            ac3.z = fmaf(al.w, xe.z, ac3.z); ac3.w = fmaf(al.w, xe.w, ac3.w);
        }
        float4* cp = reinterpret_cast<float4*>(cpart);
        cp[(wvi * 4 + 0) * 64 + lane] = ac0;
        cp[(wvi * 4 + 1) * 64 + lane] = ac1;
        cp[(wvi * 4 + 2) * 64 + lane] = ac2;
        cp[(wvi * 4 + 3) * 64 + lane] = ac3;
    }
    __syncthreads();

    if (tid < 256) {
        const int h = tid;
        float v0 = 0.f, v1 = 0.f, v2 = 0.f, v3 = 0.f;
#pragma unroll
        for (int sg = 0; sg < 8; ++sg) {
            v0 += cpart[(sg * 4 + 0) * 256 + h];
            v1 += cpart[(sg * 4 + 1) * 256 + h];
            v2 += cpart[(sg * 4 + 2) * 256 + h];
            v3 += cpart[(sg * 4 + 3) * 256 + h];
        }
        ct4[h] = make_float4(v0 * rs[0], v1 * rs[1], v2 * rs[2], v3 * rs[3]);
    }
    __syncthreads();

    {
        const float4* w2t4 = reinterpret_cast<const float4*>(w2t);
        float4 op0 = make_float4(0, 0, 0, 0), op1 = op0, op2 = op0, op3 = op0;
#pragma unroll 4
        for (int hi = 0; hi < 32; ++hi) {
            const int h = wvi * 32 + hi;
            const float4 wv4 = w2t4[(size_t)h * 64 + lane];
            const float4 cl = ct4[h];
            op0.x = fmaf(cl.x, wv4.x, op0.x); op0.y = fmaf(cl.x, wv4.y, op0.y);
            op0.z = fmaf(cl.x, wv4.z, op0.z); op0.w = fmaf(cl.x, wv4.w, op0.w);
            op1.x = fmaf(cl.y, wv4.x, op1.x); op1.y = fmaf(cl.y, wv4.y, op1.y);
            op1.z = fmaf(cl.y, wv4.z, op1.z); op1.w = fmaf(cl.y, wv4.w, op1.w);
            op2.x = fmaf(cl.z, wv4.x, op2.x); op2.y = fmaf(cl.z, wv4.y, op2.y);
            op2.z = fmaf(cl.z, wv4.z, op2.z); op2.w = fmaf(cl.z, wv4.w, op2.w);
            op3.x = fmaf(cl.w, wv4.x, op3.x); op3.y = fmaf(cl.w, wv4.y, op3.y);
            op3.z = fmaf(cl.w, wv4.z, op3.z); op3.w = fmaf(cl.w, wv4.w, op3.w);
        }
        opart[(wvi * 4 + 0) * 64 + lane] = op0;
        opart[(wvi * 4 + 1) * 64 + lane] = op1;
        opart[(wvi * 4 + 2) * 64 + lane] = op2;
        opart[(wvi * 4 + 3) * 64 + lane] = op3;
    }
    __syncthreads();

    if (tid < 256) {
        const int o4 = tid & 63, tl2 = tid >> 6;
        float4 s = make_float4(0, 0, 0, 0);
#pragma unroll
        for (int kg = 0; kg < 8; ++kg) {
            const float4 p = opart[(kg * 4 + tl2) * 64 + o4];
            s.x += p.x; s.y += p.y; s.z += p.z; s.w += p.w;
        }
        const int t = tbase + tl2;
        const float4 qo = reinterpret_cast<const float4*>(
            oq + (size_t)(b * NT + t) * NH)[o4];
        float4 r;
        r.x = fast_tanh(s.x + qo.x);
        r.y = fast_tanh(s.y + qo.y);
        r.z = fast_tanh(s.z + qo.z);
        r.w = fast_tanh(s.w + qo.w);
        reinterpret_cast<float4*>(out + (size_t)(b * NT + t) * NH)[o4] = r;
    }
}

extern "C" void kernel_launch(void* const* d_in, const int* in_sizes, int n_in,
                              void* d_out, int out_size, void* d_ws, size_t ws_size,
                              hipStream_t stream) {
    const float* q    = (const float*)d_in[0];  // (B,T,H)
    const float* enc  = (const float*)d_in[1];  // (B,S,H)
    const int*   lens = (const int*)d_in[2];    // (B,)
    const float* Ws   = (const float*)d_in[3];  // (H,H)
    const float* Wh   = (const float*)d_in[4];  // (H,H)
    const float* v    = (const float*)d_in[5];  // (H,)
    const float* Wout = (const float*)d_in[6];  // (H,2H)
    float* out = (float*)d_out;                 // (B,T,H)

    float4* peP = (float4*)d_ws;                       // NB*64*NS f4
    float* pq  = (float*)d_ws + (size_t)NB * NH * NS;  // NB*NT*NH
    float* oq  = pq + (size_t)NB * NT * NH;            // NB*NT*NH
    float* w2t = oq + (size_t)NB * NT * NH;            // NH*NH
    float* w   = w2t + (size_t)NH * NH;                // NH
    float* e   = w + NH;                               // NB*NT*NS

    kA_proj<<<208, 256, 0, stream>>>(enc, q, Wh, Ws, Wout, v, peP, pq, oq, w2t, w);
    kB_score<<<dim3(8, 8, 4), 512, 0, stream>>>(peP, pq, w, e);
    kC_ctx_out<<<dim3(32, 4), 512, 0, stream>>>(e, enc, lens, w2t, oq, out);
}

// Round 17
// 45.201 us; speedup vs baseline: 5.6434x; 1.0179x over previous
//
#include <hip/hip_runtime.h>
#include <math.h>

#define NB 4
#define NT 128
#define NS 512
#define NH 256

// pe/pq are prescaled by 2*log2(e) so exp(2z) == exp2(pe'+pq')
#define SCALE_2LOG2E 2.8853900817779268f

__device__ __forceinline__ float fast_exp2(float x) {
#if __has_builtin(__builtin_amdgcn_exp2f)
    return __builtin_amdgcn_exp2f(x);
#else
    return __expf(x * 0.6931471805599453f);
#endif
}

__device__ __forceinline__ float fast_tanh(float x) {
    // tanh(x) = 1 - 2/(exp(2x)+1); safe at +/-inf
    float e = __expf(2.0f * x);
    return 1.0f - 2.0f / (e + 1.0f);
}

__device__ __forceinline__ float dot4(float4 a, float4 b, float acc) {
    acc = fmaf(a.x, b.x, acc);
    acc = fmaf(a.y, b.y, acc);
    acc = fmaf(a.z, b.z, acc);
    acc = fmaf(a.w, b.w, acc);
    return acc;
}

// ---------------------------------------------------------------------------
// 64x64-tile GEMM core (R10/R12, proven): both operands LDS, 4x4 reg tile.
// ---------------------------------------------------------------------------
__device__ __forceinline__ void gemm_tile_64x64(
    float4* __restrict__ wsh, float4* __restrict__ xsh,
    const float* __restrict__ Wp, int wstride,
    const float* __restrict__ Xp,
    int kchunks, int tid, float acc[4][4])
{
    const int o0 = (tid & 15) * 4;
    const int m0 = (tid >> 4) * 4;
    const int srow = tid >> 2, sjl = tid & 3;
    const int wslotx = (tid & 7);
    const int xslotx = ((tid >> 4) & 7);

    for (int ck = 0; ck < kchunks; ++ck) {
        __syncthreads();
        {
            const float4* src = reinterpret_cast<const float4*>(
                Wp + (size_t)srow * wstride + ck * 128);
            const int rsw = (srow >> 2) & 7;
#pragma unroll
            for (int k = 0; k < 8; ++k) {
                const int j = sjl + 4 * k;
                wsh[srow * 32 + ((j & 31) ^ rsw)] = src[j];
            }
        }
        {
            const float4* src = reinterpret_cast<const float4*>(
                Xp + (size_t)srow * NH + ck * 128);
            const int rsw = (srow >> 2) & 7;
#pragma unroll
            for (int k = 0; k < 8; ++k) {
                const int j = sjl + 4 * k;
                xsh[srow * 32 + ((j & 31) ^ rsw)] = src[j];
            }
        }
        __syncthreads();

#pragma unroll 4
        for (int k4 = 0; k4 < 32; ++k4) {
            float4 wv0 = wsh[(o0 + 0) * 32 + (k4 ^ wslotx)];
            float4 wv1 = wsh[(o0 + 1) * 32 + (k4 ^ wslotx)];
            float4 wv2 = wsh[(o0 + 2) * 32 + (k4 ^ wslotx)];
            float4 wv3 = wsh[(o0 + 3) * 32 + (k4 ^ wslotx)];
            float4 xv0 = xsh[(m0 + 0) * 32 + (k4 ^ xslotx)];
            float4 xv1 = xsh[(m0 + 1) * 32 + (k4 ^ xslotx)];
            float4 xv2 = xsh[(m0 + 2) * 32 + (k4 ^ xslotx)];
            float4 xv3 = xsh[(m0 + 3) * 32 + (k4 ^ xslotx)];
            acc[0][0] = dot4(xv0, wv0, acc[0][0]);
            acc[0][1] = dot4(xv0, wv1, acc[0][1]);
            acc[0][2] = dot4(xv0, wv2, acc[0][2]);
            acc[0][3] = dot4(xv0, wv3, acc[0][3]);
            acc[1][0] = dot4(xv1, wv0, acc[1][0]);
            acc[1][1] = dot4(xv1, wv1, acc[1][1]);
            acc[1][2] = dot4(xv1, wv2, acc[1][2]);
            acc[1][3] = dot4(xv1, wv3, acc[1][3]);
            acc[2][0] = dot4(xv2, wv0, acc[2][0]);
            acc[2][1] = dot4(xv2, wv1, acc[2][1]);
            acc[2][2] = dot4(xv2, wv2, acc[2][2]);
            acc[2][3] = dot4(xv2, wv3, acc[2][3]);
            acc[3][0] = dot4(xv3, wv0, acc[3][0]);
            acc[3][1] = dot4(xv3, wv1, acc[3][1]);
            acc[3][2] = dot4(xv3, wv2, acc[3][2]);
            acc[3][3] = dot4(xv3, wv3, acc[3][3]);
        }
    }
}

// ---------------------------------------------------------------------------
// kA: projections + W2 transpose (R14, best measured).
// ---------------------------------------------------------------------------
__global__ __launch_bounds__(256, 2) void kA_proj(
    const float* __restrict__ enc, const float* __restrict__ q,
    const float* __restrict__ Wh, const float* __restrict__ Ws,
    const float* __restrict__ Wout, const float* __restrict__ v,
    float4* __restrict__ peP, float* __restrict__ pq,
    float* __restrict__ oq, float* __restrict__ w2t, float* __restrict__ w)
{
    __shared__ float4 wsh[64 * 32];
    __shared__ float4 xsh[64 * 32];

    const int bx = blockIdx.x;
    const int tid = threadIdx.x;

    if (bx >= 192) {
        // transpose W2 tile (64 o x 64 k) via padded LDS
        float* tl = reinterpret_cast<float*>(wsh);   // 64*65*4 = 16.6 KB
        const int bi = bx - 192;
        const int oi = bi & 3, ki = bi >> 2;
        const int row = tid >> 2, jl = tid & 3;
        {
            const float4* src = reinterpret_cast<const float4*>(
                Wout + (size_t)(oi * 64 + row) * (2 * NH) + NH + ki * 64);
#pragma unroll
            for (int kk = 0; kk < 4; ++kk) {
                const int j = jl + 4 * kk;
                const float4 val = src[j];
                tl[(4 * j + 0) * 65 + row] = val.x;
                tl[(4 * j + 1) * 65 + row] = val.y;
                tl[(4 * j + 2) * 65 + row] = val.z;
                tl[(4 * j + 3) * 65 + row] = val.w;
            }
        }
        __syncthreads();
        {
#pragma unroll
            for (int kk = 0; kk < 4; ++kk) {
                const int j = jl + 4 * kk;
                float4 val;
                val.x = tl[row * 65 + 4 * j + 0];
                val.y = tl[row * 65 + 4 * j + 1];
                val.z = tl[row * 65 + 4 * j + 2];
                val.w = tl[row * 65 + 4 * j + 3];
                reinterpret_cast<float4*>(
                    w2t + (size_t)(ki * 64 + row) * NH + oi * 64)[j] = val;
            }
        }
        return;
    }

    float acc[4][4];
#pragma unroll
    for (int i = 0; i < 4; ++i)
#pragma unroll
        for (int j = 0; j < 4; ++j) acc[i][j] = 0.f;

    if (bx == 128) w[tid] = -2.0f * v[tid];

    const int o0 = (tid & 15) * 4;
    const int m0 = (tid >> 4) * 4;

    if (bx < 128) {
        const int mt = bx >> 2, ot = bx & 3;
        const int m_base = mt * 64;
        gemm_tile_64x64(wsh, xsh, Wh + (size_t)(ot * 64) * NH, NH,
                        enc + (size_t)m_base * NH, 2, tid, acc);
        const int b = m_base >> 9, s_base = m_base & (NS - 1);
        const int quad = ot * 16 + (tid & 15);
#pragma unroll
        for (int i = 0; i < 4; ++i) {
            peP[(size_t)(b * 64 + quad) * NS + s_base + m0 + i] =
                make_float4(acc[i][0] * SCALE_2LOG2E, acc[i][1] * SCALE_2LOG2E,
                            acc[i][2] * SCALE_2LOG2E, acc[i][3] * SCALE_2LOG2E);
        }
    } else if (bx < 160) {
        const int bi = bx - 128;
        const int mt = bi >> 2, ot = bi & 3;
        const int m_base = mt * 64;
        gemm_tile_64x64(wsh, xsh, Ws + (size_t)(ot * 64) * NH, NH,
                        q + (size_t)m_base * NH, 2, tid, acc);
#pragma unroll
        for (int i = 0; i < 4; ++i) {
            *reinterpret_cast<float4*>(
                pq + (size_t)(m_base + m0 + i) * NH + ot * 64 + o0) =
                make_float4(acc[i][0] * SCALE_2LOG2E, acc[i][1] * SCALE_2LOG2E,
                            acc[i][2] * SCALE_2LOG2E, acc[i][3] * SCALE_2LOG2E);
        }
    } else {
        const int bi = bx - 160;
        const int mt = bi >> 2, ot = bi & 3;
        const int m_base = mt * 64;
        gemm_tile_64x64(wsh, xsh, Wout + (size_t)(ot * 64) * (2 * NH), 2 * NH,
                        q + (size_t)m_base * NH, 2, tid, acc);
#pragma unroll
        for (int i = 0; i < 4; ++i) {
            *reinterpret_cast<float4*>(
                oq + (size_t)(m_base + m0 + i) * NH + ot * 64 + o0) =
                make_float4(acc[i][0], acc[i][1], acc[i][2], acc[i][3]);
        }
    }
}

// ---------------------------------------------------------------------------
// kB: scores, 2 t-rows per thread (R12, best measured). Trans/VALU-issue
// bound at ~75% VALUBusy (R15); 1 block/CU — occupancy fix measured neutral
// (R16), pipe-saturated.
// ---------------------------------------------------------------------------
__global__ __launch_bounds__(512) void kB_score(
    const float4* __restrict__ peP, const float* __restrict__ pq,
    const float* __restrict__ w, float* __restrict__ e)
{
    __shared__ float4 pp[64 * 64];    // 64 KB
    __shared__ float4 pqs[16 * 64];   // 16 KB
    __shared__ float4 wls[64];        // 1 KB

    const int sx = blockIdx.x;
    const int ty = blockIdx.y;
    const int b  = blockIdx.z;
    const int tid = threadIdx.x;
    const int t0 = ty * 16;

    {
        const int row = tid >> 3, jl = tid & 7;
        const float4* src = peP + (size_t)(b * 64 + row) * NS + sx * 64;
#pragma unroll
        for (int k = 0; k < 8; ++k) pp[row * 64 + jl + 8 * k] = src[jl + 8 * k];
    }
    {
        const int r = tid >> 5, j = tid & 31;
        const float4* src = reinterpret_cast<const float4*>(
            pq + (size_t)(b * NT + t0 + r) * NH);
        pqs[r * 64 + j] = src[j];
        pqs[r * 64 + j + 32] = src[j + 32];
    }
    if (tid < 64) wls[tid] = reinterpret_cast<const float4*>(w)[tid];
    __syncthreads();

    const int lane = tid & 63;
    const int wvi  = tid >> 6;
    const int tA = wvi, tB = wvi + 8;

    float a0 = 0.f, a1 = 0.f, a2 = 0.f, a3 = 0.f;
    float b0 = 0.f, b1 = 0.f, b2 = 0.f, b3 = 0.f;
#pragma unroll 4
    for (int h4 = 0; h4 < 64; ++h4) {
        const float4 pv = pp[h4 * 64 + lane];
        const float4 qa = pqs[tA * 64 + h4];
        const float4 qb = pqs[tB * 64 + h4];
        const float4 wl = wls[h4];
        a0 = fmaf(wl.x, __builtin_amdgcn_rcpf(fast_exp2(pv.x + qa.x) + 1.0f), a0);
        a1 = fmaf(wl.y, __builtin_amdgcn_rcpf(fast_exp2(pv.y + qa.y) + 1.0f), a1);
        a2 = fmaf(wl.z, __builtin_amdgcn_rcpf(fast_exp2(pv.z + qa.z) + 1.0f), a2);
        a3 = fmaf(wl.w, __builtin_amdgcn_rcpf(fast_exp2(pv.w + qa.w) + 1.0f), a3);
        b0 = fmaf(wl.x, __builtin_amdgcn_rcpf(fast_exp2(pv.x + qb.x) + 1.0f), b0);
        b1 = fmaf(wl.y, __builtin_amdgcn_rcpf(fast_exp2(pv.y + qb.y) + 1.0f), b1);
        b2 = fmaf(wl.z, __builtin_amdgcn_rcpf(fast_exp2(pv.z + qb.z) + 1.0f), b2);
        b3 = fmaf(wl.w, __builtin_amdgcn_rcpf(fast_exp2(pv.w + qb.w) + 1.0f), b3);
    }
    e[(size_t)(b * NT + t0 + tA) * NS + sx * 64 + lane] = (a0 + a1) + (a2 + a3);
    e[(size_t)(b * NT + t0 + tB) * NS + sx * 64 + lane] = (b0 + b1) + (b2 + b3);
}

// ---------------------------------------------------------------------------
// kC: fused masked-softmax + context + output projection (R12, best measured).
// ---------------------------------------------------------------------------
__global__ __launch_bounds__(512) void kC_ctx_out(
    const float* __restrict__ e, const float* __restrict__ enc,
    const int* __restrict__ lens, const float* __restrict__ w2t,
    const float* __restrict__ oq, float* __restrict__ out)
{
    __shared__ __align__(16) unsigned char smem[45088];
    float4* pt    = reinterpret_cast<float4*>(smem);            // 8 KB [512]
    float*  cpart = reinterpret_cast<float*>(smem + 8192);      // 32 KB
    float4* opart = reinterpret_cast<float4*>(smem + 8192);     // alias
    float4* ct4   = reinterpret_cast<float4*>(smem + 40960);    // 4 KB
    float*  rs    = reinterpret_cast<float*>(smem + 45056);     // 16 B

    const int tt = blockIdx.x;
    const int b  = blockIdx.y;
    const int tid = threadIdx.x;
    const int lane = tid & 63;
    const int wvi  = tid >> 6;
    const int tbase = tt * 4;
    const int len = lens[b];

    if (wvi < 4) {
        const int t = tbase + wvi;
        const float4* erow = reinterpret_cast<const float4*>(
            e + (size_t)(b * NT + t) * NS);
        float4 va = erow[lane];
        float4 vb = erow[lane + 64];
        const int c0 = 4 * lane, c1 = 256 + 4 * lane;
        if (c0 + 0 >= len) va.x = -INFINITY;
        if (c0 + 1 >= len) va.y = -INFINITY;
        if (c0 + 2 >= len) va.z = -INFINITY;
        if (c0 + 3 >= len) va.w = -INFINITY;
        if (c1 + 0 >= len) vb.x = -INFINITY;
        if (c1 + 1 >= len) vb.y = -INFINITY;
        if (c1 + 2 >= len) vb.z = -INFINITY;
        if (c1 + 3 >= len) vb.w = -INFINITY;

        float m = fmaxf(fmaxf(fmaxf(va.x, va.y), fmaxf(va.z, va.w)),
                        fmaxf(fmaxf(vb.x, vb.y), fmaxf(vb.z, vb.w)));
#pragma unroll
        for (int off = 32; off; off >>= 1) m = fmaxf(m, __shfl_xor(m, off));

        va.x = __expf(va.x - m); va.y = __expf(va.y - m);
        va.z = __expf(va.z - m); va.w = __expf(va.w - m);
        vb.x = __expf(vb.x - m); vb.y = __expf(vb.y - m);
        vb.z = __expf(vb.z - m); vb.w = __expf(vb.w - m);

        float sum = va.x + va.y + va.z + va.w + vb.x + vb.y + vb.z + vb.w;
#pragma unroll
        for (int off = 32; off; off >>= 1) sum += __shfl_xor(sum, off);
        if (lane == 0) rs[wvi] = 1.0f / sum;

        float* ptf = reinterpret_cast<float*>(pt);
        ptf[(c0 + 0) * 4 + wvi] = va.x;
        ptf[(c0 + 1) * 4 + wvi] = va.y;
        ptf[(c0 + 2) * 4 + wvi] = va.z;
        ptf[(c0 + 3) * 4 + wvi] = va.w;
        ptf[(c1 + 0) * 4 + wvi] = vb.x;
        ptf[(c1 + 1) * 4 + wvi] = vb.y;
        ptf[(c1 + 2) * 4 + wvi] = vb.z;
        ptf[(c1 + 3) * 4 + wvi] = vb.w;
    }
    __syncthreads();

    {
        const float4* enc4 = reinterpret_cast<const float4*>(
            enc + (size_t)b * NS * NH) + (size_t)wvi * 64 * 64 + lane;
        float4 ac0 = make_float4(0, 0, 0, 0), ac1 = ac0, ac2 = ac0, ac3 = ac0;
#pragma unroll 4
        for (int si = 0; si < 64; ++si) {
            const float4 xe = enc4[(size_t)si * 64];
            const float4 al = pt[wvi * 64 + si];
            ac0.x = fmaf(al.x, xe.x, ac0.x); ac0.y = fmaf(al.x, xe.y, ac0.y);
            ac0.z = fmaf(al.x, xe.z, ac0.z); ac0.w = fmaf(al.x, xe.w, ac0.w);
            ac1.x = fmaf(al.y, xe.x, ac1.x); ac1.y = fmaf(al.y, xe.y, ac1.y);
            ac1.z = fmaf(al.y, xe.z, ac1.z); ac1.w = fmaf(al.y, xe.w, ac1.w);
            ac2.x = fmaf(al.z, xe.x, ac2.x); ac2.y = fmaf(al.z, xe.y, ac2.y);
            ac2.z = fmaf(al.z, xe.z, ac2.z); ac2.w = fmaf(al.z, xe.w, ac2.w);
            ac3.x = fmaf(al.w, xe.x, ac3.x); ac3.y = fmaf(al.w, xe.y, ac3.y);
            ac3.z = fmaf(al.w, xe.z, ac3.z); ac3.w = fmaf(al.w, xe.w, ac3.w);
        }
        float4* cp = reinterpret_cast<float4*>(cpart);
        cp[(wvi * 4 + 0) * 64 + lane] = ac0;
        cp[(wvi * 4 + 1) * 64 + lane] = ac1;
        cp[(wvi * 4 + 2) * 64 + lane] = ac2;
        cp[(wvi * 4 + 3) * 64 + lane] = ac3;
    }
    __syncthreads();

    if (tid < 256) {
        const int h = tid;
        float v0 = 0.f, v1 = 0.f, v2 = 0.f, v3 = 0.f;
#pragma unroll
        for (int sg = 0; sg < 8; ++sg) {
            v0 += cpart[(sg * 4 + 0) * 256 + h];
            v1 += cpart[(sg * 4 + 1) * 256 + h];
            v2 += cpart[(sg * 4 + 2) * 256 + h];
            v3 += cpart[(sg * 4 + 3) * 256 + h];
        }
        ct4[h] = make_float4(v0 * rs[0], v1 * rs[1], v2 * rs[2], v3 * rs[3]);
    }
    __syncthreads();

    {
        const float4* w2t4 = reinterpret_cast<const float4*>(w2t);
        float4 op0 = make_float4(0, 0, 0, 0), op1 = op0, op2 = op0, op3 = op0;
#pragma unroll 4
        for (int hi = 0; hi < 32; ++hi) {
            const int h = wvi * 32 + hi;
            const float4 wv4 = w2t4[(size_t)h * 64 + lane];
            const float4 cl = ct4[h];
            op0.x = fmaf(cl.x, wv4.x, op0.x); op0.y = fmaf(cl.x, wv4.y, op0.y);
            op0.z = fmaf(cl.x, wv4.z, op0.z); op0.w = fmaf(cl.x, wv4.w, op0.w);
            op1.x = fmaf(cl.y, wv4.x, op1.x); op1.y = fmaf(cl.y, wv4.y, op1.y);
            op1.z = fmaf(cl.y, wv4.z, op1.z); op1.w = fmaf(cl.y, wv4.w, op1.w);
            op2.x = fmaf(cl.z, wv4.x, op2.x); op2.y = fmaf(cl.z, wv4.y, op2.y);
            op2.z = fmaf(cl.z, wv4.z, op2.z); op2.w = fmaf(cl.z, wv4.w, op2.w);
            op3.x = fmaf(cl.w, wv4.x, op3.x); op3.y = fmaf(cl.w, wv4.y, op3.y);
            op3.z = fmaf(cl.w, wv4.z, op3.z); op3.w = fmaf(cl.w, wv4.w, op3.w);
        }
        opart[(wvi * 4 + 0) * 64 + lane] = op0;
        opart[(wvi * 4 + 1) * 64 + lane] = op1;
        opart[(wvi * 4 + 2) * 64 + lane] = op2;
        opart[(wvi * 4 + 3) * 64 + lane] = op3;
    }
    __syncthreads();

    if (tid < 256) {
        const int o4 = tid & 63, tl2 = tid >> 6;
        float4 s = make_float4(0, 0, 0, 0);
#pragma unroll
        for (int kg = 0; kg < 8; ++kg) {
            const float4 p = opart[(kg * 4 + tl2) * 64 + o4];
            s.x += p.x; s.y += p.y; s.z += p.z; s.w += p.w;
        }
        const int t = tbase + tl2;
        const float4 qo = reinterpret_cast<const float4*>(
            oq + (size_t)(b * NT + t) * NH)[o4];
        float4 r;
        r.x = fast_tanh(s.x + qo.x);
        r.y = fast_tanh(s.y + qo.y);
        r.z = fast_tanh(s.z + qo.z);
        r.w = fast_tanh(s.w + qo.w);
        reinterpret_cast<float4*>(out + (size_t)(b * NT + t) * NH)[o4] = r;
    }
}

extern "C" void kernel_launch(void* const* d_in, const int* in_sizes, int n_in,
                              void* d_out, int out_size, void* d_ws, size_t ws_size,
                              hipStream_t stream) {
    const float* q    = (const float*)d_in[0];  // (B,T,H)
    const float* enc  = (const float*)d_in[1];  // (B,S,H)
    const int*   lens = (const int*)d_in[2];    // (B,)
    const float* Ws   = (const float*)d_in[3];  // (H,H)
    const float* Wh   = (const float*)d_in[4];  // (H,H)
    const float* v    = (const float*)d_in[5];  // (H,)
    const float* Wout = (const float*)d_in[6];  // (H,2H)
    float* out = (float*)d_out;                 // (B,T,H)

    float4* peP = (float4*)d_ws;                       // NB*64*NS f4
    float* pq  = (float*)d_ws + (size_t)NB * NH * NS;  // NB*NT*NH
    float* oq  = pq + (size_t)NB * NT * NH;            // NB*NT*NH
    float* w2t = oq + (size_t)NB * NT * NH;            // NH*NH
    float* w   = w2t + (size_t)NH * NH;                // NH
    float* e   = w + NH;                               // NB*NT*NS

    kA_proj<<<208, 256, 0, stream>>>(enc, q, Wh, Ws, Wout, v, peP, pq, oq, w2t, w);
    kB_score<<<dim3(8, 8, 4), 512, 0, stream>>>(peP, pq, w, e);
    kC_ctx_out<<<dim3(32, 4), 512, 0, stream>>>(e, enc, lens, w2t, oq, out);
}